// Round 13
// baseline (223.263 us; speedup 1.0000x reference)
//
#include <hip/hip_runtime.h>
#include <cstdint>

#define NB 2
#define NN 1024
#define MM 2048
#define DD 512
#define HH 64
#define ST 68          // padded LDS stride (floats)
#define STB 72         // padded LDS stride (ushorts)

typedef __attribute__((ext_vector_type(8))) short bf16x8;
typedef __attribute__((ext_vector_type(4))) float f32x4;

__device__ inline ushort f2bf(float x) {
  union { float f; uint32_t u; } v; v.f = x;
  uint32_t u = v.u;
  u += 0x7FFF + ((u >> 16) & 1);      // RNE
  return (ushort)(u >> 16);
}
__device__ inline float bflo(uint32_t d) { return __uint_as_float(d << 16); }
__device__ inline float bfhi(uint32_t d) { return __uint_as_float(d & 0xFFFF0000u); }

#define GLDS(gp, lp) \
  __builtin_amdgcn_global_load_lds( \
      (const __attribute__((address_space(1))) void*)(gp), \
      (__attribute__((address_space(3))) void*)(lp), 16, 0, 0)

// ==== prep: WgT conv + update->(Ubf0,UT) conv + cand->out copy + lr0 ====
__global__ __launch_bounds__(256) void prep_kernel(
    const float* __restrict__ Wg, ushort* __restrict__ WgT,
    const float* __restrict__ update, ushort* __restrict__ Ubf0,
    ushort* __restrict__ UT, const float* __restrict__ cand,
    float* __restrict__ out, const float* __restrict__ Wl,
    const float* __restrict__ Wr, float* __restrict__ left,
    ushort* __restrict__ right_bf) {
  __shared__ __align__(16) char smem[16640];
  const int bid = blockIdx.x;
  const int tid = threadIdx.x;
  const int tx = tid & 15, ty = tid >> 4;

  if (bid < 384) {
    const float* in;
    ushort* out_row;
    ushort* out_T;
    int R, C, r0, c0;
    if (bid < 128) {
      in = Wg; out_row = nullptr; out_T = WgT;
      R = 2 * DD; C = DD; r0 = (bid >> 3) * 64; c0 = (bid & 7) * 64;
    } else {
      const int t = bid - 128, b = t >> 7, rem = t & 127;
      in = update + (size_t)b * NN * DD;
      out_row = Ubf0 + (size_t)b * NN * DD;
      out_T = UT + (size_t)b * DD * NN;
      R = NN; C = DD; r0 = (rem >> 3) * 64; c0 = (rem & 7) * 64;
    }
    float (*tile)[65] = (float(*)[65])smem;
#pragma unroll
    for (int p = 0; p < 4; ++p) {
      const int r = ty + p * 16;
      const float4 v = *(const float4*)&in[(size_t)(r0 + r) * C + c0 + tx * 4];
      tile[r][tx * 4 + 0] = v.x; tile[r][tx * 4 + 1] = v.y;
      tile[r][tx * 4 + 2] = v.z; tile[r][tx * 4 + 3] = v.w;
      if (out_row) {
        ushort4 o = make_ushort4(f2bf(v.x), f2bf(v.y), f2bf(v.z), f2bf(v.w));
        *(ushort4*)&out_row[(size_t)(r0 + r) * C + c0 + tx * 4] = o;
      }
    }
    __syncthreads();
#pragma unroll
    for (int p = 0; p < 4; ++p) {
      const int rr = ty + p * 16;
      ushort4 o;
      o.x = f2bf(tile[tx * 4 + 0][rr]);
      o.y = f2bf(tile[tx * 4 + 1][rr]);
      o.z = f2bf(tile[tx * 4 + 2][rr]);
      o.w = f2bf(tile[tx * 4 + 3][rr]);
      *(ushort4*)&out_T[(size_t)(c0 + rr) * R + r0 + tx * 4] = o;
    }
    __syncthreads();
  }

  // ---- lr0: 4 rows per block ----
  {
    float (*u)[DD] = (float(*)[DD])smem;
    const float4* Uv = (const float4*)(update + (size_t)bid * 4 * DD);
    float4* uv = (float4*)&u[0][0];
#pragma unroll
    for (int t = 0; t < 2; ++t) uv[tid + t * 256] = Uv[tid + t * 256];
    __syncthreads();
    const int h = tid & 63;
    const int isR = (tid >> 6) & 1;
    const int rsel = tid >> 7;
    const float* __restrict__ W = isR ? Wr : Wl;
    float acc[2] = {0.f, 0.f};
    for (int k0 = 0; k0 < DD; k0 += 4) {
      float w0 = W[(k0 + 0) * HH + h];
      float w1 = W[(k0 + 1) * HH + h];
      float w2 = W[(k0 + 2) * HH + h];
      float w3 = W[(k0 + 3) * HH + h];
#pragma unroll
      for (int r = 0; r < 2; ++r) {
        float4 u4 = *(const float4*)&u[rsel + r * 2][k0];
        acc[r] = fmaf(u4.w, w3, fmaf(u4.z, w2, fmaf(u4.y, w1, fmaf(u4.x, w0, acc[r]))));
      }
    }
    if (isR) {
#pragma unroll
      for (int r = 0; r < 2; ++r)
        right_bf[(size_t)(bid * 4 + rsel + r * 2) * HH + h] = f2bf(acc[r]);
    } else {
#pragma unroll
      for (int r = 0; r < 2; ++r)
        left[(size_t)(bid * 4 + rsel + r * 2) * HH + h] = acc[r];
    }
  }

  // ---- cand -> out head copy ----
  {
    const float4* c4 = (const float4*)cand;
    float4* o4 = (float4*)out;
    for (int idx = bid * 256 + tid; idx < NB * MM * DD / 4; idx += 512 * 256)
      o4[idx] = c4[idx];
  }
}

// ---- standalone lr (iteration 1) ----
__global__ __launch_bounds__(256) void lr_kernel(
    const float* __restrict__ U, const float* __restrict__ Wl,
    const float* __restrict__ Wr, float* __restrict__ left,
    ushort* __restrict__ right_bf) {
  __shared__ float u[4][DD];
  const int bid = blockIdx.x;
  const int tid = threadIdx.x;
  const float4* Uv = (const float4*)(U + (size_t)bid * 4 * DD);
  float4* uv = (float4*)&u[0][0];
#pragma unroll
  for (int t = 0; t < 2; ++t) uv[tid + t * 256] = Uv[tid + t * 256];
  __syncthreads();
  const int h = tid & 63;
  const int isR = (tid >> 6) & 1;
  const int rsel = tid >> 7;
  const float* __restrict__ W = isR ? Wr : Wl;
  float acc[2] = {0.f, 0.f};
  for (int k0 = 0; k0 < DD; k0 += 4) {
    float w0 = W[(k0 + 0) * HH + h];
    float w1 = W[(k0 + 1) * HH + h];
    float w2 = W[(k0 + 2) * HH + h];
    float w3 = W[(k0 + 3) * HH + h];
#pragma unroll
    for (int r = 0; r < 2; ++r) {
      float4 u4 = *(const float4*)&u[rsel + r * 2][k0];
      acc[r] = fmaf(u4.w, w3, fmaf(u4.z, w2, fmaf(u4.y, w1, fmaf(u4.x, w0, acc[r]))));
    }
  }
  if (isR) {
#pragma unroll
    for (int r = 0; r < 2; ++r)
      right_bf[(size_t)(bid * 4 + rsel + r * 2) * HH + h] = f2bf(acc[r]);
  } else {
#pragma unroll
    for (int r = 0; r < 2; ++r)
      left[(size_t)(bid * 4 + rsel + r * 2) * HH + h] = acc[r];
  }
}

// ---- fused score + softmax. Rt double-buffered: global loads for chunk c+1
// issued before compute of chunk c; one barrier per chunk (8 vs 16). ----
__global__ __launch_bounds__(256) void score_softmax(
    const float* __restrict__ left, const ushort* __restrict__ right_bf,
    const int* __restrict__ span_begin, const float* __restrict__ mask,
    const float* __restrict__ dist_emb, const float* __restrict__ b_h,
    const float* __restrict__ v_out, ushort* __restrict__ probs_bf) {
  __shared__ ushort Rt[2][128][STB];   // 36.9 KB (double buffer)
  __shared__ ushort LDb[4][10][STB];   //  5.8 KB
  __shared__ float Dbh[10][ST];        //  2.7 KB
  __shared__ float Lt[4][ST];          //  1.1 KB
  __shared__ float Sc[4][NN];          // 16.0 KB
  __shared__ int sbj[NN];              //  4.0 KB   (total ~66.5 KB, 2 blk/CU)
  const int b = blockIdx.y;
  const int r0 = blockIdx.x * 4;
  const int tid = threadIdx.x;
  const int wave = tid >> 6, lane = tid & 63;
  const int row = r0 + wave;

  for (int f = tid; f < 160; f += 256) {
    int bk = f >> 4, h4 = f & 15;
    float4 d = *(const float4*)&dist_emb[bk * HH + h4 * 4];
    float4 bh = *(const float4*)&b_h[h4 * 4];
    d.x += bh.x; d.y += bh.y; d.z += bh.z; d.w += bh.w;
    *(float4*)&Dbh[bk][h4 * 4] = d;
  }
  if (tid < 64) {
    int r = tid >> 4, h4 = tid & 15;
    *(float4*)&Lt[r][h4 * 4] =
        *(const float4*)&left[((size_t)b * NN + r0 + r) * HH + h4 * 4];
  }
  for (int t = tid; t < NN; t += 256) sbj[t] = span_begin[b * NN + t];
  __syncthreads();
  for (int f = tid; f < 2560; f += 256) {
    int i = f / 640;
    int rem = f - i * 640;
    int bk = rem >> 6, h = rem & 63;
    LDb[i][bk][h] = f2bf(Lt[i][h] + Dbh[bk][h]);
  }
  float4 vr[16];
#pragma unroll
  for (int hq = 0; hq < 16; ++hq) vr[hq] = *(const float4*)&v_out[hq * 4];
  const int my_sbi = span_begin[(size_t)b * NN + row];
  const float* maskrow = mask + ((size_t)b * NN + row) * NN;
  const ushort* rbase = right_bf + (size_t)b * NN * HH;

  bf16x8 stg[4];
  // prologue: stage chunk 0 into Rt[0]
#pragma unroll
  for (int t = 0; t < 4; ++t) {
    const int f = tid + t * 256;
    stg[t] = *(const bf16x8*)&rbase[(size_t)(f >> 3) * HH + (f & 7) * 8];
  }
#pragma unroll
  for (int t = 0; t < 4; ++t) {
    const int f = tid + t * 256;
    *(bf16x8*)&Rt[0][f >> 3][(f & 7) * 8] = stg[t];
  }

#pragma unroll 1
  for (int c = 0; c < 8; ++c) {
    if (c + 1 < 8) {                   // issue next chunk's loads (overlap compute)
#pragma unroll
      for (int t = 0; t < 4; ++t) {
        const int f = tid + t * 256;
        stg[t] = *(const bf16x8*)&rbase[(size_t)((c + 1) * 128 + (f >> 3)) * HH +
                                        (f & 7) * 8];
      }
    }
    __syncthreads();                   // Rt[c&1] ready (prev ds_writes + LDb)
    float mv[2];
    mv[0] = maskrow[c * 128 + lane];
    mv[1] = maskrow[c * 128 + 64 + lane];
#pragma unroll
    for (int half = 0; half < 2; ++half) {
      const int j = c * 128 + half * 64 + lane;
      int d = sbj[j] - my_sbi;
      d = d < 0 ? -d : d;
      const int bk =
          d <= 4 ? d : (d <= 7 ? 5 : (d <= 15 ? 6 : (d <= 31 ? 7 : (d <= 63 ? 8 : 9))));
      const ushort* zp = &LDb[wave][bk][0];
      const ushort* rp = &Rt[c & 1][half * 64 + lane][0];
      float acc0 = 0.f, acc1 = 0.f;
#pragma unroll
      for (int oct = 0; oct < 8; oct += 2) {
        {
          const uint4 zd = *(const uint4*)&zp[oct * 8];
          const uint4 rd = *(const uint4*)&rp[oct * 8];
          const float4 v0 = vr[2 * oct], v1 = vr[2 * oct + 1];
          acc0 = fmaf(fmaxf(bflo(zd.x) + bflo(rd.x), 0.f), v0.x, acc0);
          acc0 = fmaf(fmaxf(bfhi(zd.x) + bfhi(rd.x), 0.f), v0.y, acc0);
          acc0 = fmaf(fmaxf(bflo(zd.y) + bflo(rd.y), 0.f), v0.z, acc0);
          acc0 = fmaf(fmaxf(bfhi(zd.y) + bfhi(rd.y), 0.f), v0.w, acc0);
          acc0 = fmaf(fmaxf(bflo(zd.z) + bflo(rd.z), 0.f), v1.x, acc0);
          acc0 = fmaf(fmaxf(bfhi(zd.z) + bfhi(rd.z), 0.f), v1.y, acc0);
          acc0 = fmaf(fmaxf(bflo(zd.w) + bflo(rd.w), 0.f), v1.z, acc0);
          acc0 = fmaf(fmaxf(bfhi(zd.w) + bfhi(rd.w), 0.f), v1.w, acc0);
        }
        {
          const uint4 zd = *(const uint4*)&zp[(oct + 1) * 8];
          const uint4 rd = *(const uint4*)&rp[(oct + 1) * 8];
          const float4 v0 = vr[2 * oct + 2], v1 = vr[2 * oct + 3];
          acc1 = fmaf(fmaxf(bflo(zd.x) + bflo(rd.x), 0.f), v0.x, acc1);
          acc1 = fmaf(fmaxf(bfhi(zd.x) + bfhi(rd.x), 0.f), v0.y, acc1);
          acc1 = fmaf(fmaxf(bflo(zd.y) + bflo(rd.y), 0.f), v0.z, acc1);
          acc1 = fmaf(fmaxf(bfhi(zd.y) + bfhi(rd.y), 0.f), v0.w, acc1);
          acc1 = fmaf(fmaxf(bflo(zd.z) + bflo(rd.z), 0.f), v1.x, acc1);
          acc1 = fmaf(fmaxf(bfhi(zd.z) + bfhi(rd.z), 0.f), v1.y, acc1);
          acc1 = fmaf(fmaxf(bflo(zd.w) + bflo(rd.w), 0.f), v1.z, acc1);
          acc1 = fmaf(fmaxf(bfhi(zd.w) + bfhi(rd.w), 0.f), v1.w, acc1);
        }
      }
      Sc[wave][j] = (acc0 + acc1) - (1.0f - mv[half]) * 1e23f;
    }
    if (c + 1 < 8) {                   // commit prefetched chunk to other buffer
#pragma unroll
      for (int t = 0; t < 4; ++t) {
        const int f = tid + t * 256;
        *(bf16x8*)&Rt[(c + 1) & 1][f >> 3][(f & 7) * 8] = stg[t];
      }
    }
  }
  float mx = -3.0e38f;
#pragma unroll
  for (int c = 0; c < 16; ++c) mx = fmaxf(mx, Sc[wave][c * 64 + lane]);
#pragma unroll
  for (int off = 32; off; off >>= 1) mx = fmaxf(mx, __shfl_xor(mx, off));
  float sum = 0.f;
#pragma unroll
  for (int c = 0; c < 16; ++c) {
    const float e = __expf(Sc[wave][c * 64 + lane] - mx);
    Sc[wave][c * 64 + lane] = e;
    sum += e;
  }
#pragma unroll
  for (int off = 32; off; off >>= 1) sum += __shfl_xor(sum, off);
  const float inv = 1.0f / sum;
  ushort* prow = probs_bf + ((size_t)b * NN + row) * NN;
#pragma unroll
  for (int c = 0; c < 16; ++c)
    prow[c * 64 + lane] = f2bf(Sc[wave][c * 64 + lane] * inv);
}

// -------- ctxt(bf16) = P @ U, 32x64 tile, BK=128, DOUBLE-BUFFERED LDS --------
__global__ __launch_bounds__(256) void gemm_ctxt_mfma(
    const ushort* __restrict__ Pbf, const ushort* __restrict__ UT,
    ushort* __restrict__ Cbf) {
  __shared__ ushort As[2][32 * 128];   // 16 KB
  __shared__ ushort Bs[2][64 * 128];   // 32 KB
  const int b = blockIdx.z;
  const int m0 = blockIdx.y * 32, n0 = blockIdx.x * 64;
  const int tid = threadIdx.x;
  const int lane = tid & 63, wave = tid >> 6;
  const int wm = (wave >> 1) * 16, wn = (wave & 1) * 32;
  const ushort* Ab = Pbf + (size_t)b * NN * NN;
  const ushort* Bb = UT + (size_t)b * DD * NN;
  f32x4 acc[2] = {};
  const int fm = lane & 15, quad = lane >> 4;

#define CTXT_STAGE(buf, kk)                                                  \
  do {                                                                       \
    _Pragma("unroll") for (int t = 0; t < 2; ++t) {                          \
      const int idx = tid + t * 256;                                         \
      const int r = idx >> 4, c16 = idx & 15;                                \
      const int g = c16 ^ (r & 15);                                          \
      GLDS(Ab + (size_t)(m0 + r) * NN + (kk) + g * 8, &As[buf][idx * 8]);    \
    }                                                                        \
    _Pragma("unroll") for (int t = 0; t < 4; ++t) {                          \
      const int idx = tid + t * 256;                                         \
      const int r = idx >> 4, c16 = idx & 15;                                \
      const int g = c16 ^ (r & 15);                                          \
      GLDS(Bb + (size_t)(n0 + r) * NN + (kk) + g * 8, &Bs[buf][idx * 8]);    \
    }                                                                        \
  } while (0)

  CTXT_STAGE(0, 0);
#pragma unroll 1
  for (int k = 0; k < 8; ++k) {
    __syncthreads();                   // vmcnt drain: buf[k&1] ready
    if (k + 1 < 8) CTXT_STAGE((k + 1) & 1, (k + 1) * 128);
    const int cur = k & 1;
#pragma unroll
    for (int s = 0; s < 4; ++s) {
      bf16x8 af, bfr[2];
      {
        const int row = wm + fm;
        const int c16 = (s * 4 + quad) ^ (row & 15);
        af = *(const bf16x8*)&As[cur][row * 128 + c16 * 8];
      }
#pragma unroll
      for (int tn = 0; tn < 2; ++tn) {
        const int row = wn + tn * 16 + fm;
        const int c16 = (s * 4 + quad) ^ (row & 15);
        bfr[tn] = *(const bf16x8*)&Bs[cur][row * 128 + c16 * 8];
      }
#pragma unroll
      for (int tn = 0; tn < 2; ++tn)
        acc[tn] = __builtin_amdgcn_mfma_f32_16x16x32_bf16(af, bfr[tn], acc[tn], 0, 0, 0);
    }
  }
#pragma unroll
  for (int tn = 0; tn < 2; ++tn) {
    const int col = n0 + wn + tn * 16 + fm;
#pragma unroll
    for (int r = 0; r < 4; ++r) {
      const int row = m0 + wm + quad * 4 + r;
      Cbf[(size_t)b * NN * DD + (size_t)row * DD + col] = f2bf(acc[tn][r]);
    }
  }
}

// -------- gate GEMM 32x64, BK=128, DOUBLE-BUFFERED + sigmoid/blend epilogue --------
__global__ __launch_bounds__(256) void gemm_gate_mfma(
    const ushort* __restrict__ Ubf, const ushort* __restrict__ Cbf,
    const ushort* __restrict__ WgT, const float* __restrict__ bg,
    const float* __restrict__ Uf, float* __restrict__ Uout,
    ushort* __restrict__ UbfOut, ushort* __restrict__ UTOut,
    const int* __restrict__ prune, const int* __restrict__ span_len,
    float* __restrict__ out_cand, int final_it) {
  __shared__ ushort As[2][32 * 128];
  __shared__ ushort Bs[2][64 * 128];
  __shared__ ushort Tt[32][66];
  const int b = blockIdx.z;
  const int m0 = blockIdx.y * 32, n0 = blockIdx.x * 64;
  const int tid = threadIdx.x;
  const int lane = tid & 63, wave = tid >> 6;
  const int wm = (wave >> 1) * 16, wn = (wave & 1) * 32;
  f32x4 acc[2] = {};
  const int fm = lane & 15, quad = lane >> 4;
  const ushort* Au = Ubf + (size_t)b * NN * DD;
  const ushort* Ac = Cbf + (size_t)b * NN * DD;

#define GATE_STAGE(buf, kk)                                                  \
  do {                                                                       \
    const ushort* Abase = ((kk) < DD) ? Au : Ac;                             \
    const int kc = (kk) & (DD - 1);                                          \
    _Pragma("unroll") for (int t = 0; t < 2; ++t) {                          \
      const int idx = tid + t * 256;                                         \
      const int r = idx >> 4, c16 = idx & 15;                                \
      const int g = c16 ^ (r & 15);                                          \
      GLDS(Abase + (size_t)(m0 + r) * DD + kc + g * 8, &As[buf][idx * 8]);   \
    }                                                                        \
    _Pragma("unroll") for (int t = 0; t < 4; ++t) {                          \
      const int idx = tid + t * 256;                                         \
      const int r = idx >> 4, c16 = idx & 15;                                \
      const int g = c16 ^ (r & 15);                                          \
      GLDS(WgT + (size_t)(n0 + r) * (2 * DD) + (kk) + g * 8, &Bs[buf][idx * 8]); \
    }                                                                        \
  } while (0)

  GATE_STAGE(0, 0);
#pragma unroll 1
  for (int k = 0; k < 8; ++k) {
    __syncthreads();
    if (k + 1 < 8) GATE_STAGE((k + 1) & 1, (k + 1) * 128);
    const int cur = k & 1;
#pragma unroll
    for (int s = 0; s < 4; ++s) {
      bf16x8 af, bfr[2];
      {
        const int row = wm + fm;
        const int c16 = (s * 4 + quad) ^ (row & 15);
        af = *(const bf16x8*)&As[cur][row * 128 + c16 * 8];
      }
#pragma unroll
      for (int tn = 0; tn < 2; ++tn) {
        const int row = wn + tn * 16 + fm;
        const int c16 = (s * 4 + quad) ^ (row & 15);
        bfr[tn] = *(const bf16x8*)&Bs[cur][row * 128 + c16 * 8];
      }
#pragma unroll
      for (int tn = 0; tn < 2; ++tn)
        acc[tn] = __builtin_amdgcn_mfma_f32_16x16x32_bf16(af, bfr[tn], acc[tn], 0, 0, 0);
    }
  }
  const int slen = span_len[b];
#pragma unroll
  for (int tn = 0; tn < 2; ++tn) {
    const int cl = wn + tn * 16 + fm;
    const int col = n0 + cl;
    const float bgv = bg[col];
#pragma unroll
    for (int r = 0; r < 4; ++r) {
      const int rl = wm + quad * 4 + r;
      const int row = m0 + rl;
      const size_t off = (size_t)b * NN * DD + (size_t)row * DD + col;
      const float g = 1.f / (1.f + __expf(-(acc[tn][r] + bgv)));
      const float cv = __uint_as_float(((uint32_t)Cbf[off]) << 16);
      const float o = g * Uf[off] + (1.f - g) * cv;
      Uout[off] = o;
      if (final_it) {
        if (row < slen) {
          const int dst = prune[b * NN + row];
          out_cand[((size_t)b * MM + dst) * DD + col] = o;
        }
      } else {
        const ushort ob = f2bf(o);
        UbfOut[off] = ob;
        Tt[rl][cl] = ob;
      }
    }
  }
  if (!final_it) {
    __syncthreads();
#pragma unroll
    for (int p = 0; p < 2; ++p) {
      const int cl = (tid >> 3) + p * 32;
      const int rl = (tid & 7) * 4;
      ushort4 o;
      o.x = Tt[rl + 0][cl]; o.y = Tt[rl + 1][cl];
      o.z = Tt[rl + 2][cl]; o.w = Tt[rl + 3][cl];
      *(ushort4*)&UTOut[((size_t)b * DD + n0 + cl) * NN + m0 + rl] = o;
    }
  }
}

extern "C" void kernel_launch(void* const* d_in, const int* in_sizes, int n_in,
                              void* d_out, int out_size, void* d_ws, size_t ws_size,
                              hipStream_t stream) {
  const float* update = (const float*)d_in[0];
  const float* mask = (const float*)d_in[1];
  const float* cand = (const float*)d_in[2];
  const int* span_begin = (const int*)d_in[3];
  const int* prune = (const int*)d_in[5];
  const int* span_len = (const int*)d_in[6];
  const float* Wl = (const float*)d_in[7];
  const float* Wr = (const float*)d_in[8];
  const float* b_h = (const float*)d_in[9];
  const float* dist_emb = (const float*)d_in[10];
  const float* v_out = (const float*)d_in[11];
  const float* Wg = (const float*)d_in[13];
  const float* b_gate = (const float*)d_in[14];

  char* w = (char*)d_ws;
  float* left = (float*)w;        w += (size_t)NB * NN * HH * 4;   // 512 KB
  ushort* right_bf = (ushort*)w;  w += (size_t)NB * NN * HH * 2;   // 256 KB
  ushort* probs_bf = (ushort*)w;  w += (size_t)NB * NN * NN * 2;   // 4 MB
  ushort* ctxt_bf = (ushort*)w;   w += (size_t)NB * NN * DD * 2;   // 2 MB
  float* upd1 = (float*)w;        w += (size_t)NB * NN * DD * 4;   // 4 MB
  ushort* Ubf0 = (ushort*)w;      w += (size_t)NB * NN * DD * 2;   // 2 MB
  ushort* Ubf1 = (ushort*)w;      w += (size_t)NB * NN * DD * 2;   // 2 MB
  ushort* UT = (ushort*)w;        w += (size_t)NB * NN * DD * 2;   // 2 MB
  ushort* WgT = (ushort*)w;       w += (size_t)2 * DD * DD * 2;    // 1 MB

  float* out = (float*)d_out;
  float* out_upd = out + (size_t)NB * MM * DD;

  prep_kernel<<<512, 256, 0, stream>>>(Wg, WgT, update, Ubf0, UT, cand, out,
                                       Wl, Wr, left, right_bf);
  // iteration 0
  score_softmax<<<dim3(NN / 4, NB), 256, 0, stream>>>(
      left, right_bf, span_begin, mask, dist_emb, b_h, v_out, probs_bf);
  gemm_ctxt_mfma<<<dim3(8, 32, NB), 256, 0, stream>>>(probs_bf, UT, ctxt_bf);
  gemm_gate_mfma<<<dim3(8, 32, NB), 256, 0, stream>>>(
      Ubf0, ctxt_bf, WgT, b_gate, update, upd1, Ubf1, UT,
      prune, span_len, out, 0);
  // iteration 1
  lr_kernel<<<512, 256, 0, stream>>>(upd1, Wl, Wr, left, right_bf);
  score_softmax<<<dim3(NN / 4, NB), 256, 0, stream>>>(
      left, right_bf, span_begin, mask, dist_emb, b_h, v_out, probs_bf);
  gemm_ctxt_mfma<<<dim3(8, 32, NB), 256, 0, stream>>>(probs_bf, UT, ctxt_bf);
  gemm_gate_mfma<<<dim3(8, 32, NB), 256, 0, stream>>>(
      Ubf1, ctxt_bf, WgT, b_gate, upd1, out_upd, nullptr, nullptr,
      prune, span_len, out, 1);
}